// Round 20
// baseline (177.900 us; speedup 1.0000x reference)
//
#include <hip/hip_runtime.h>
#include <stdint.h>

// ---------------- types ----------------
typedef short bf16x8 __attribute__((ext_vector_type(8)));
typedef float f32x4  __attribute__((ext_vector_type(4)));

__device__ __forceinline__ uint16_t f2bf(float f) {
    uint32_t u = __float_as_uint(f);
    u += 0x7FFF + ((u >> 16) & 1);   // round-to-nearest-even
    return (uint16_t)(u >> 16);
}
__device__ __forceinline__ uint32_t pk2bf(float a, float b) {
    return (uint32_t)f2bf(a) | ((uint32_t)f2bf(b) << 16);
}

typedef __attribute__((address_space(1))) const uint32_t gu32;
typedef __attribute__((address_space(3))) uint32_t lu32;
__device__ __forceinline__ void gload16(const void* g, void* l) {
    __builtin_amdgcn_global_load_lds((gu32*)g, (lu32*)l, 16, 0, 0);
}

// =====================================================================
// prep: all prologue work in one kernel (r13-16-verified, incl. X cvt).
// =====================================================================
__global__ __launch_bounds__(256) void prep(
    const float* __restrict__ X,  const float* __restrict__ W1,
    const float* __restrict__ W2, const float* __restrict__ W3,
    uint16_t* __restrict__ xbf, uint16_t* __restrict__ w1t,
    uint16_t* __restrict__ w2t, uint16_t* __restrict__ w3t)
{
    const int b = blockIdx.x, tid = threadIdx.x;
    if (b < 4096) {
        const int i = b * 256 + tid;
        const float4 v = ((const float4*)X)[i];
        ushort4 h;
        h.x = f2bf(v.x); h.y = f2bf(v.y); h.z = f2bf(v.z); h.w = f2bf(v.w);
        ((ushort4*)xbf)[i] = h;
        return;
    }
    __shared__ float t[32][33];
    const int tx = tid & 31, ty = tid >> 5;
    const float* in; uint16_t* out; int R, C, bx, by, e;
    if (b < 5120) {
        const int bb = b - 4096; e = bb >> 7; const int rem = bb & 127;
        bx = rem & 15; by = rem >> 4; R = 256; C = 512; in = W1; out = w1t;
    } else if (b < 7168) {
        const int bb = b - 5120; e = bb >> 8; const int rem = bb & 255;
        bx = rem & 15; by = rem >> 4; R = 512; C = 512; in = W2; out = w2t;
    } else {
        const int bb = b - 7168; e = bb >> 4; bx = 0; by = bb & 15;
        R = 512; C = 32; in = W3; out = w3t;
    }
    const int r0 = by * 32, c0 = bx * 32;
    const float* ine = in + (size_t)e * R * C;
    uint16_t* oute   = out + (size_t)e * R * C;
#pragma unroll
    for (int j = 0; j < 4; ++j)
        t[ty + 8 * j][tx] = ine[(size_t)(r0 + ty + 8 * j) * C + (c0 + tx)];
    __syncthreads();
#pragma unroll
    for (int j = 0; j < 4; ++j) {
        const int orow = c0 + ty + 8 * j;
        const int ocol = r0 + tx;
        oute[(size_t)orow * R + ocol] = f2bf(t[tx][ty + 8 * j]);
    }
}

// =====================================================================
// fused64s: r16 dataflow at BM=64 with 80KB LDS -> 2 BLOCKS/CU.
// Rationale: 9 engine variants were null because all waves share one
// barrier domain (r17: more waves in-domain = null). Two independent
// blocks/CU interleave (m114): one block's barrier/drain dead time is
// filled by the other's MFMA phases.
// Block = 64 batch rows x one e, 8 waves. Grid (8e, 256) -> XCD = e.
// LDS 80KB: [0,64K) h1 [64][1024B] bf16 swz (X pre-staged in [0,32K)
// as 4 subtiles [64][64k]@8KB; L1 acc in regs); [64K,80K) wstg
// 2 x 8KB W dbuf ([64n][64k]) / h2-octant [64][128B] after drain.
// Engine = r12-verified 2-phase; swizzle = r7-verified; MFMA maps =
// r6+/r10-verified (swapped: D col(lane&15)=batch row, row(kg*4+v)=n).
// L1/L2 wave grid 2m(32rows) x 4n(16cols/tile); L3 4m x 2o.
// =====================================================================
__global__ __launch_bounds__(512, 4) void fused64s(
    const uint16_t* __restrict__ xbf,
    const uint16_t* __restrict__ W1t, const float* __restrict__ b1,
    const uint16_t* __restrict__ W2t, const float* __restrict__ b2,
    const uint16_t* __restrict__ W3t, const float* __restrict__ b3,
    float* __restrict__ out)
{
    extern __shared__ char smem[];
    char* h1buf = smem;             // 64KB: X subtiles then h1 [64][1024B]
    char* wstg  = smem + 65536;     // 16KB: 2 x 8KB W dbuf / h2oct

    const int tid = threadIdx.x, wid = tid >> 6, lane = tid & 63;
    const int kg = lane >> 4, lr = lane & 15;
    const int e   = blockIdx.x;
    const int bm0 = blockIdx.y * 64;
    const int wm = wid >> 2, wn = wid & 3;        // L1/L2: 2m x 4n
    const int rlo = lane >> 3, pslot = lane & 7;
    const int lswz = (pslot ^ rlo) * 8;

    const uint16_t* Xb  = xbf + (size_t)bm0 * 256;
    const uint16_t* W1e = W1t + (size_t)e * 512 * 256;
    const uint16_t* W2e = W2t + (size_t)e * 512 * 512;
    const uint16_t* W3e = W3t + (size_t)e * 32 * 512;

    // stage W tile [64n][64k] (8KB): wave covers rows wid*8..+7 (1KB)
    auto stageW = [&](const uint16_t* We, int K, int s, int nq, int kt) {
        const int r = wid * 8 + rlo;                         // r&7 == rlo
        gload16(We + (size_t)(nq * 64 + r) * K + kt * 64 + lswz,
                wstg + s * 8192 + wid * 1024 + lane * 16);
    };

    // ---- prologue: X [64][256] as 4 subtiles + W1 (nq0,kt0) ----
#pragma unroll
    for (int kt = 0; kt < 4; ++kt) {
        const int r = wid * 8 + rlo;
        gload16(Xb + (size_t)r * 256 + kt * 64 + lswz,
                h1buf + kt * 8192 + wid * 1024 + lane * 16);
    }
    stageW(W1e, 256, 0, 0, 0);
    __syncthreads();

    // ================= LAYER 1 (K=256): acc in registers ===============
    f32x4 a1[8][2];                  // [nq][b] = 64 VGPR-equiv
#pragma unroll
    for (int q = 0; q < 8; ++q)
#pragma unroll
        for (int b = 0; b < 2; ++b) a1[q][b] = f32x4{0.f, 0.f, 0.f, 0.f};

#pragma unroll
    for (int p = 0; p < 32; ++p) {   // p = nq*4 + kt
        const int nq = p >> 2, kt = p & 3, cur = p & 1;
        if (p + 1 < 32) stageW(W1e, 256, cur ^ 1, (p + 1) >> 2, (p + 1) & 3);
        asm volatile("" ::: "memory");
        __builtin_amdgcn_s_setprio(1);
#pragma unroll
        for (int kh = 0; kh < 2; ++kh) {
            bf16x8 wf, af[2];
            {
                const int row = wn * 16 + lr;
                wf = *(const bf16x8*)(wstg + cur * 8192 + row * 128 +
                                      (((kh * 4 + kg) ^ (row & 7)) << 4));
            }
#pragma unroll
            for (int b = 0; b < 2; ++b) {
                const int row = wm * 32 + b * 16 + lr;
                af[b] = *(const bf16x8*)(h1buf + kt * 8192 + row * 128 +
                                         (((kh * 4 + kg) ^ (row & 7)) << 4));
            }
#pragma unroll
            for (int b = 0; b < 2; ++b)
                a1[nq][b] = __builtin_amdgcn_mfma_f32_16x16x32_bf16(wf, af[b], a1[nq][b], 0, 0, 0);
        }
        __builtin_amdgcn_s_setprio(0);
        __syncthreads();
    }

    // ---- L1 epilogue (X dead): bias+relu -> h1 [64][1024B] swz ----
#pragma unroll
    for (int nq = 0; nq < 8; ++nq) {
        const int col = nq * 64 + wn * 16 + kg * 4;
        const float4 bv = *(const float4*)(b1 + e * 512 + col);
#pragma unroll
        for (int b = 0; b < 2; ++b) {
            const float x0 = fmaxf(a1[nq][b][0] + bv.x, 0.f);
            const float x1 = fmaxf(a1[nq][b][1] + bv.y, 0.f);
            const float x2 = fmaxf(a1[nq][b][2] + bv.z, 0.f);
            const float x3 = fmaxf(a1[nq][b][3] + bv.w, 0.f);
            uint2 w;
            w.x = pk2bf(x0, x1);
            w.y = pk2bf(x2, x3);
            const int row = wm * 32 + b * 16 + lr;
            *(uint2*)(h1buf + row * 1024 + (((col << 1)) ^ ((row & 7) << 4))) = w;
        }
    }
    __syncthreads();

    // ========== LAYERS 2+3 per n-octant (h2oct -> wstg -> L3) ==========
    const int mf = wid >> 1, of = wid & 1;        // L3: 4m x 2o
    f32x4 o3 = f32x4{0.f, 0.f, 0.f, 0.f};

#pragma unroll
    for (int nq = 0; nq < 8; ++nq) {
        stageW(W2e, 512, 0, nq, 0);
        __syncthreads();

        f32x4 a2[2];
        a2[0] = f32x4{0.f, 0.f, 0.f, 0.f};
        a2[1] = f32x4{0.f, 0.f, 0.f, 0.f};

#pragma unroll
        for (int kt = 0; kt < 8; ++kt) {
            const int cur = kt & 1;
            if (kt + 1 < 8) stageW(W2e, 512, cur ^ 1, nq, kt + 1);
            asm volatile("" ::: "memory");
            __builtin_amdgcn_s_setprio(1);
#pragma unroll
            for (int kh = 0; kh < 2; ++kh) {
                bf16x8 wf, af[2];
                {
                    const int row = wn * 16 + lr;
                    wf = *(const bf16x8*)(wstg + cur * 8192 + row * 128 +
                                          (((kh * 4 + kg) ^ (row & 7)) << 4));
                }
                const int kbyte = kt * 128 + kh * 64 + kg * 16;
#pragma unroll
                for (int b = 0; b < 2; ++b) {
                    const int row = wm * 32 + b * 16 + lr;
                    af[b] = *(const bf16x8*)(h1buf + row * 1024 +
                                             (kbyte ^ ((row & 7) << 4)));
                }
#pragma unroll
                for (int b = 0; b < 2; ++b)
                    a2[b] = __builtin_amdgcn_mfma_f32_16x16x32_bf16(wf, af[b], a2[b], 0, 0, 0);
            }
            __builtin_amdgcn_s_setprio(0);
            __syncthreads();
        }

        // epilogue: bias+relu -> h2oct in wstg slot0 [64][128B] swz
        {
            const int colh = wn * 16 + kg * 4;               // 0..63
            const float4 bv = *(const float4*)(b2 + e * 512 + nq * 64 + colh);
#pragma unroll
            for (int b = 0; b < 2; ++b) {
                const float x0 = fmaxf(a2[b][0] + bv.x, 0.f);
                const float x1 = fmaxf(a2[b][1] + bv.y, 0.f);
                const float x2 = fmaxf(a2[b][2] + bv.z, 0.f);
                const float x3 = fmaxf(a2[b][3] + bv.w, 0.f);
                uint2 w;
                w.x = pk2bf(x0, x1);
                w.y = pk2bf(x2, x3);
                const int row = wm * 32 + b * 16 + lr;
                *(uint2*)(wstg + row * 128 + (((colh << 1)) ^ ((row & 7) << 4))) = w;
            }
        }
        __syncthreads();

        // L3 partial: o3 += h2oct @ W3[:, nq*64..+64)
        // swapped: D=mfma(W3 frag [o][k], h2 frag [m][k]) ->
        //   col(lane&15)=m-row, row(kg*4+v)=o-col  (r10/r15/r16-verified)
#pragma unroll
        for (int kc = 0; kc < 2; ++kc) {
            const int row = mf * 16 + lr;
            const bf16x8 hb = *(const bf16x8*)(wstg + row * 128 +
                                               ((kc * 64 + kg * 16) ^ ((row & 7) << 4)));
            const bf16x8 w3 = *(const bf16x8*)(W3e + (size_t)(of * 16 + lr) * 512 +
                                               nq * 64 + kc * 32 + kg * 8);
            o3 = __builtin_amdgcn_mfma_f32_16x16x32_bf16(w3, hb, o3, 0, 0, 0);
        }
        __syncthreads();   // L3 LDS reads retired; wstg free for next nq
    }

    // ---- final store: bias3 + float4, row-contiguous (r17-verified) ----
    {
        const int col = e * 32 + of * 16 + kg * 4;
        const float4 bv = *(const float4*)(b3 + col);
        const int row = bm0 + mf * 16 + lr;
        float4 res;
        res.x = o3[0] + bv.x;
        res.y = o3[1] + bv.y;
        res.z = o3[2] + bv.z;
        res.w = o3[3] + bv.w;
        *(float4*)(out + (size_t)row * 256 + col) = res;
    }
}

// ---------------- host launch ----------------
extern "C" void kernel_launch(void* const* d_in, const int* in_sizes, int n_in,
                              void* d_out, int out_size, void* d_ws, size_t ws_size,
                              hipStream_t stream) {
    (void)in_sizes; (void)n_in; (void)out_size; (void)ws_size;
    const float* X  = (const float*)d_in[0];   // [16384,256]
    const float* W1 = (const float*)d_in[1];   // [8,256,512]
    const float* b1 = (const float*)d_in[2];   // [8,512]
    const float* W2 = (const float*)d_in[3];   // [8,512,512]
    const float* b2 = (const float*)d_in[4];   // [8,512]
    const float* W3 = (const float*)d_in[5];   // [8,512,32]
    const float* b3 = (const float*)d_in[6];   // [8,32]
    float* out = (float*)d_out;                // [16384,8,32]

    uint16_t* w1t = (uint16_t*)d_ws;           // [8][512][256] bf16  (2 MB)
    uint16_t* w2t = w1t + 8 * 256 * 512;       // [8][512][512] bf16  (4 MB)
    uint16_t* w3t = w2t + 8 * 512 * 512;       // [8][32][512]  bf16  (256 KB)
    uint16_t* xbf = w3t + 8 * 512 * 32;        // [16384][256]  bf16  (8 MB)

    prep<<<7296, 256, 0, stream>>>(X, W1, W2, W3, xbf, w1t, w2t, w3t);

    (void)hipFuncSetAttribute((const void*)fused64s,
                              hipFuncAttributeMaxDynamicSharedMemorySize, 81920);
    fused64s<<<dim3(8, 256), 512, 81920, stream>>>(xbf, w1t, b1, w2t, b2,
                                                   w3t, b3, out);
}

// Round 21
// 142.759 us; speedup vs baseline: 1.2462x; 1.2462x over previous
//
#include <hip/hip_runtime.h>
#include <stdint.h>

// ---------------- types ----------------
typedef short bf16x8 __attribute__((ext_vector_type(8)));
typedef float f32x4  __attribute__((ext_vector_type(4)));

__device__ __forceinline__ uint16_t f2bf(float f) {
    uint32_t u = __float_as_uint(f);
    u += 0x7FFF + ((u >> 16) & 1);   // round-to-nearest-even
    return (uint16_t)(u >> 16);
}
__device__ __forceinline__ uint32_t pk2bf(float a, float b) {
    return (uint32_t)f2bf(a) | ((uint32_t)f2bf(b) << 16);
}

typedef __attribute__((address_space(1))) const uint32_t gu32;
typedef __attribute__((address_space(3))) uint32_t lu32;
__device__ __forceinline__ void gload16(const void* g, void* l) {
    __builtin_amdgcn_global_load_lds((gu32*)g, (lu32*)l, 16, 0, 0);
}

// =====================================================================
// prep: all prologue work in one kernel (r13-16-verified).
// =====================================================================
__global__ __launch_bounds__(256) void prep(
    const float* __restrict__ X,  const float* __restrict__ W1,
    const float* __restrict__ W2, const float* __restrict__ W3,
    uint16_t* __restrict__ xbf, uint16_t* __restrict__ w1t,
    uint16_t* __restrict__ w2t, uint16_t* __restrict__ w3t)
{
    const int b = blockIdx.x, tid = threadIdx.x;
    if (b < 4096) {
        const int i = b * 256 + tid;
        const float4 v = ((const float4*)X)[i];
        ushort4 h;
        h.x = f2bf(v.x); h.y = f2bf(v.y); h.z = f2bf(v.z); h.w = f2bf(v.w);
        ((ushort4*)xbf)[i] = h;
        return;
    }
    __shared__ float t[32][33];
    const int tx = tid & 31, ty = tid >> 5;
    const float* in; uint16_t* out; int R, C, bx, by, e;
    if (b < 5120) {
        const int bb = b - 4096; e = bb >> 7; const int rem = bb & 127;
        bx = rem & 15; by = rem >> 4; R = 256; C = 512; in = W1; out = w1t;
    } else if (b < 7168) {
        const int bb = b - 5120; e = bb >> 8; const int rem = bb & 255;
        bx = rem & 15; by = rem >> 4; R = 512; C = 512; in = W2; out = w2t;
    } else {
        const int bb = b - 7168; e = bb >> 4; bx = 0; by = bb & 15;
        R = 512; C = 32; in = W3; out = w3t;
    }
    const int r0 = by * 32, c0 = bx * 32;
    const float* ine = in + (size_t)e * R * C;
    uint16_t* oute   = out + (size_t)e * R * C;
#pragma unroll
    for (int j = 0; j < 4; ++j)
        t[ty + 8 * j][tx] = ine[(size_t)(r0 + ty + 8 * j) * C + (c0 + tx)];
    __syncthreads();
#pragma unroll
    for (int j = 0; j < 4; ++j) {
        const int orow = c0 + ty + 8 * j;
        const int ocol = r0 + tx;
        oute[(size_t)orow * R + ocol] = f2bf(t[tx][ty + 8 * j]);
    }
}

// =====================================================================
// fused128c: r16's fused128 (145us champion) with ONE change: the
// h1/h2q swizzle granule moves 16B -> 32B ((row&7)<<5). Analysis:
// with <<4, kg*16 (addr bits 4-5) aliases the swizzle bits 4-6 ->
// L2 af reads and both epilogues are 4-way bank-conflicted (1.58x,
// m136) = the invariant 1.15e7 conflict cycles (13% of runtime).
// With <<5 the write pattern spreads 32 distinct 8B offsets over all
// banks (2-way, free) and the kg in {0,2}/{1,3} read pairs become
// same-row same-address BROADCASTS. Bijective: XOR on bits 5-7 within
// both 1024B (h1) and 256B (h2q) row strides. The gload-path tiles
// (X subtiles, W staging) keep their verified 16B swizzle.
// Everything else is r16-byte-identical.
// =====================================================================
__global__ __launch_bounds__(512, 1) void fused128c(
    const uint16_t* __restrict__ xbf,
    const uint16_t* __restrict__ W1t, const float* __restrict__ b1,
    const uint16_t* __restrict__ W2t, const float* __restrict__ b2,
    const uint16_t* __restrict__ W3t, const float* __restrict__ b3,
    float* __restrict__ out)
{
    extern __shared__ char smem[];
    char* h1buf = smem;             // 128KB  [128][1024B] bf16 swz32
    char* wstg  = smem + 131072;    // 32KB   dbuf 2x[128n][64k] / h2q [128][256B]

    const int tid = threadIdx.x, wid = tid >> 6, lane = tid & 63;
    const int kg = lane >> 4, lr = lane & 15;
    const int e   = blockIdx.x;
    const int bm0 = blockIdx.y * 128;
    const int wm = wid >> 2, wn = wid & 3;        // L1/L2: 2m x 4n waves
    const int rlo = lane >> 3, pslot = lane & 7;
    const int lswz = (pslot ^ rlo) * 8;

    const uint16_t* Xb  = xbf + (size_t)bm0 * 256;
    const uint16_t* W1e = W1t + (size_t)e * 512 * 256;
    const uint16_t* W2e = W2t + (size_t)e * 512 * 512;
    const uint16_t* W3e = W3t + (size_t)e * 32 * 512;

    // stage W tile [128n][64k] (16KB) for n-quarter nq, k-tile kt
    auto stageW = [&](const uint16_t* We, int K, int cur, int nq, int kt) {
#pragma unroll
        for (int i = 0; i < 2; ++i) {
            const int r = wid * 16 + i * 8 + rlo;            // r&7 == rlo
            gload16(We + (size_t)(nq * 128 + r) * K + kt * 64 + lswz,
                    wstg + cur * 16384 + r * 128 + lane * 16);
        }
    };

    // ---- prologue: X [128][256] as 4 subtiles into h1buf[0:64K) ----
#pragma unroll
    for (int kt = 0; kt < 4; ++kt)
#pragma unroll
        for (int i = 0; i < 2; ++i) {
            const int rb = wid * 16 + i * 8;
            gload16(Xb + (size_t)(rb + rlo) * 256 + kt * 64 + lswz,
                    h1buf + kt * 16384 + rb * 128 + lane * 16);
        }
    stageW(W1e, 256, 0, 0, 0);
    __syncthreads();

    // ================= LAYER 1 (K=256): acc fully in registers =========
    f32x4 a1[4][4][2];               // [nq][b][c] = 128 VGPR
#pragma unroll
    for (int q = 0; q < 4; ++q)
#pragma unroll
        for (int b = 0; b < 4; ++b)
#pragma unroll
            for (int c = 0; c < 2; ++c) a1[q][b][c] = f32x4{0.f, 0.f, 0.f, 0.f};

#pragma unroll
    for (int p = 0; p < 16; ++p) {   // p = nq*4 + kt
        const int nq = p >> 2, kt = p & 3, cur = p & 1;
        if (p + 1 < 16) stageW(W1e, 256, cur ^ 1, (p + 1) >> 2, (p + 1) & 3);
        asm volatile("" ::: "memory");
        __builtin_amdgcn_s_setprio(1);
#pragma unroll
        for (int kh = 0; kh < 2; ++kh) {
            bf16x8 wf[2], af[4];
#pragma unroll
            for (int c = 0; c < 2; ++c) {
                const int row = wn * 32 + c * 16 + lr;
                wf[c] = *(const bf16x8*)(wstg + cur * 16384 + row * 128 +
                                         (((kh * 4 + kg) ^ (row & 7)) << 4));
            }
#pragma unroll
            for (int b = 0; b < 4; ++b) {
                const int row = wm * 64 + b * 16 + lr;
                af[b] = *(const bf16x8*)(h1buf + kt * 16384 + row * 128 +
                                         (((kh * 4 + kg) ^ (row & 7)) << 4));
            }
#pragma unroll
            for (int b = 0; b < 4; ++b)
#pragma unroll
                for (int c = 0; c < 2; ++c)
                    a1[nq][b][c] = __builtin_amdgcn_mfma_f32_16x16x32_bf16(wf[c], af[b], a1[nq][b][c], 0, 0, 0);
        }
        __builtin_amdgcn_s_setprio(0);
        __syncthreads();
    }

    // ---- L1 epilogue (X dead): bias+relu -> h1 [128][1024B] swz32 ----
#pragma unroll
    for (int nq = 0; nq < 4; ++nq)
#pragma unroll
        for (int c = 0; c < 2; ++c) {
            const int col = nq * 128 + wn * 32 + c * 16 + kg * 4;
            const float4 bv = *(const float4*)(b1 + e * 512 + col);
#pragma unroll
            for (int b = 0; b < 4; ++b) {
                const float x0 = fmaxf(a1[nq][b][c][0] + bv.x, 0.f);
                const float x1 = fmaxf(a1[nq][b][c][1] + bv.y, 0.f);
                const float x2 = fmaxf(a1[nq][b][c][2] + bv.z, 0.f);
                const float x3 = fmaxf(a1[nq][b][c][3] + bv.w, 0.f);
                uint2 w;
                w.x = pk2bf(x0, x1);
                w.y = pk2bf(x2, x3);
                const int row = wm * 64 + b * 16 + lr;
                *(uint2*)(h1buf + row * 1024 + (((col << 1)) ^ ((row & 7) << 5))) = w;
            }
        }
    __syncthreads();

    // ========== LAYERS 2+3 per n-quarter (h2q -> wstg -> L3 partial) ====
    const int mf = wid >> 1, of = wid & 1;        // L3: 4m x 2o waves
    f32x4 o3[2];
    o3[0] = f32x4{0.f, 0.f, 0.f, 0.f};
    o3[1] = f32x4{0.f, 0.f, 0.f, 0.f};

#pragma unroll
    for (int nq = 0; nq < 4; ++nq) {
        stageW(W2e, 512, 0, nq, 0);
        __syncthreads();

        f32x4 a2[4][2];
#pragma unroll
        for (int b = 0; b < 4; ++b)
#pragma unroll
            for (int c = 0; c < 2; ++c) a2[b][c] = f32x4{0.f, 0.f, 0.f, 0.f};

#pragma unroll
        for (int kt = 0; kt < 8; ++kt) {
            const int cur = kt & 1;
            if (kt + 1 < 8) stageW(W2e, 512, cur ^ 1, nq, kt + 1);
            asm volatile("" ::: "memory");
            __builtin_amdgcn_s_setprio(1);
#pragma unroll
            for (int kh = 0; kh < 2; ++kh) {
                bf16x8 wf[2], af[4];
#pragma unroll
                for (int c = 0; c < 2; ++c) {
                    const int row = wn * 32 + c * 16 + lr;
                    wf[c] = *(const bf16x8*)(wstg + cur * 16384 + row * 128 +
                                             (((kh * 4 + kg) ^ (row & 7)) << 4));
                }
                const int kbyte = kt * 128 + kh * 64 + kg * 16;
#pragma unroll
                for (int b = 0; b < 4; ++b) {
                    const int row = wm * 64 + b * 16 + lr;
                    af[b] = *(const bf16x8*)(h1buf + row * 1024 +
                                             (kbyte ^ ((row & 7) << 5)));
                }
#pragma unroll
                for (int b = 0; b < 4; ++b)
#pragma unroll
                    for (int c = 0; c < 2; ++c)
                        a2[b][c] = __builtin_amdgcn_mfma_f32_16x16x32_bf16(wf[c], af[b], a2[b][c], 0, 0, 0);
            }
            __builtin_amdgcn_s_setprio(0);
            __syncthreads();
        }

        // epilogue: bias+relu -> h2q in wstg [128][256B] swz32
#pragma unroll
        for (int c = 0; c < 2; ++c) {
            const int colh = wn * 32 + c * 16 + kg * 4;      // 0..127
            const float4 bv = *(const float4*)(b2 + e * 512 + nq * 128 + colh);
#pragma unroll
            for (int b = 0; b < 4; ++b) {
                const float x0 = fmaxf(a2[b][c][0] + bv.x, 0.f);
                const float x1 = fmaxf(a2[b][c][1] + bv.y, 0.f);
                const float x2 = fmaxf(a2[b][c][2] + bv.z, 0.f);
                const float x3 = fmaxf(a2[b][c][3] + bv.w, 0.f);
                uint2 w;
                w.x = pk2bf(x0, x1);
                w.y = pk2bf(x2, x3);
                const int row = wm * 64 + b * 16 + lr;
                *(uint2*)(wstg + row * 256 + (((colh << 1)) ^ ((row & 7) << 5))) = w;
            }
        }
        __syncthreads();

        // L3 partial: o3 += h2q @ W3[:, nq*128..+128)  (r10/r15/r16-verified)
#pragma unroll
        for (int kcq = 0; kcq < 4; ++kcq)
#pragma unroll
            for (int b2f = 0; b2f < 2; ++b2f) {
                const int row = mf * 32 + b2f * 16 + lr;
                const bf16x8 hb = *(const bf16x8*)(wstg + row * 256 +
                                                   ((kcq * 64 + kg * 16) ^ ((row & 7) << 5)));
                const bf16x8 w3 = *(const bf16x8*)(W3e + (size_t)(of * 16 + lr) * 512 +
                                                   nq * 128 + kcq * 32 + kg * 8);
                o3[b2f] = __builtin_amdgcn_mfma_f32_16x16x32_bf16(w3, hb, o3[b2f], 0, 0, 0);
            }
        __syncthreads();   // hb reads retired; wstg free for next nq
    }

    // ---- final store: bias3 + float4, row-contiguous ----
#pragma unroll
    for (int b2f = 0; b2f < 2; ++b2f) {
        const int col = e * 32 + of * 16 + kg * 4;
        const float4 bv = *(const float4*)(b3 + col);
        const int row = bm0 + mf * 32 + b2f * 16 + lr;
        float4 res;
        res.x = o3[b2f][0] + bv.x;
        res.y = o3[b2f][1] + bv.y;
        res.z = o3[b2f][2] + bv.z;
        res.w = o3[b2f][3] + bv.w;
        *(float4*)(out + (size_t)row * 256 + col) = res;
    }
}

// ---------------- host launch ----------------
extern "C" void kernel_launch(void* const* d_in, const int* in_sizes, int n_in,
                              void* d_out, int out_size, void* d_ws, size_t ws_size,
                              hipStream_t stream) {
    (void)in_sizes; (void)n_in; (void)out_size; (void)ws_size;
    const float* X  = (const float*)d_in[0];   // [16384,256]
    const float* W1 = (const float*)d_in[1];   // [8,256,512]
    const float* b1 = (const float*)d_in[2];   // [8,512]
    const float* W2 = (const float*)d_in[3];   // [8,512,512]
    const float* b2 = (const float*)d_in[4];   // [8,512]
    const float* W3 = (const float*)d_in[5];   // [8,512,32]
    const float* b3 = (const float*)d_in[6];   // [8,32]
    float* out = (float*)d_out;                // [16384,8,32]

    uint16_t* w1t = (uint16_t*)d_ws;           // [8][512][256] bf16  (2 MB)
    uint16_t* w2t = w1t + 8 * 256 * 512;       // [8][512][512] bf16  (4 MB)
    uint16_t* w3t = w2t + 8 * 512 * 512;       // [8][32][512]  bf16  (256 KB)
    uint16_t* xbf = w3t + 8 * 512 * 32;        // [16384][256]  bf16  (8 MB)

    prep<<<7296, 256, 0, stream>>>(X, W1, W2, W3, xbf, w1t, w2t, w3t);

    (void)hipFuncSetAttribute((const void*)fused128c,
                              hipFuncAttributeMaxDynamicSharedMemorySize, 163840);
    fused128c<<<dim3(8, 128), 512, 163840, stream>>>(xbf, w1t, b1, w2t, b2,
                                                     w3t, b3, out);
}

// Round 22
// 139.508 us; speedup vs baseline: 1.2752x; 1.0233x over previous
//
#include <hip/hip_runtime.h>
#include <stdint.h>

// ---------------- types ----------------
typedef short bf16x8 __attribute__((ext_vector_type(8)));
typedef float f32x4  __attribute__((ext_vector_type(4)));

__device__ __forceinline__ uint16_t f2bf(float f) {
    uint32_t u = __float_as_uint(f);
    u += 0x7FFF + ((u >> 16) & 1);   // round-to-nearest-even
    return (uint16_t)(u >> 16);
}
__device__ __forceinline__ uint32_t pk2bf(float a, float b) {
    return (uint32_t)f2bf(a) | ((uint32_t)f2bf(b) << 16);
}

typedef __attribute__((address_space(1))) const uint32_t gu32;
typedef __attribute__((address_space(3))) uint32_t lu32;
__device__ __forceinline__ void gload16(const void* g, void* l) {
    __builtin_amdgcn_global_load_lds((gu32*)g, (lu32*)l, 16, 0, 0);
}

// =====================================================================
// prep: all prologue work in one kernel (r13-16-verified).
// =====================================================================
__global__ __launch_bounds__(256) void prep(
    const float* __restrict__ X,  const float* __restrict__ W1,
    const float* __restrict__ W2, const float* __restrict__ W3,
    uint16_t* __restrict__ xbf, uint16_t* __restrict__ w1t,
    uint16_t* __restrict__ w2t, uint16_t* __restrict__ w3t)
{
    const int b = blockIdx.x, tid = threadIdx.x;
    if (b < 4096) {
        const int i = b * 256 + tid;
        const float4 v = ((const float4*)X)[i];
        ushort4 h;
        h.x = f2bf(v.x); h.y = f2bf(v.y); h.z = f2bf(v.z); h.w = f2bf(v.w);
        ((ushort4*)xbf)[i] = h;
        return;
    }
    __shared__ float t[32][33];
    const int tx = tid & 31, ty = tid >> 5;
    const float* in; uint16_t* out; int R, C, bx, by, e;
    if (b < 5120) {
        const int bb = b - 4096; e = bb >> 7; const int rem = bb & 127;
        bx = rem & 15; by = rem >> 4; R = 256; C = 512; in = W1; out = w1t;
    } else if (b < 7168) {
        const int bb = b - 5120; e = bb >> 8; const int rem = bb & 255;
        bx = rem & 15; by = rem >> 4; R = 512; C = 512; in = W2; out = w2t;
    } else {
        const int bb = b - 7168; e = bb >> 4; bx = 0; by = bb & 15;
        R = 512; C = 32; in = W3; out = w3t;
    }
    const int r0 = by * 32, c0 = bx * 32;
    const float* ine = in + (size_t)e * R * C;
    uint16_t* oute   = out + (size_t)e * R * C;
#pragma unroll
    for (int j = 0; j < 4; ++j)
        t[ty + 8 * j][tx] = ine[(size_t)(r0 + ty + 8 * j) * C + (c0 + tx)];
    __syncthreads();
#pragma unroll
    for (int j = 0; j < 4; ++j) {
        const int orow = c0 + ty + 8 * j;
        const int ocol = r0 + tx;
        oute[(size_t)orow * R + ocol] = f2bf(t[tx][ty + 8 * j]);
    }
}

// =====================================================================
// fused128d: r21 champion (142.8us) + FAT L1 PHASES + W2 prefetch.
//  - L1 W tiles double to [256n][64k]=32KB, double-buffered in
//    h1buf[64K:128K) (FREE during L1: X occupies only [0:64K)).
//    L1: 16 thin phases -> 8 fat phases (32 MFMA/wave each). The only
//    lever that ever moved this kernel family was fatter phases.
//  - wstg is idle during L1 -> prefetch W2(nq0,kt0) before the L1
//    epilogue; its trailing __syncthreads drains it, so L2-nq0 starts
//    without its own stage+sync.
// Everything else r21-verbatim: swz32 on h1/h2q, 16B swz on gload
// tiles, 2-phase engine, swapped-MFMA maps, epilogues, L3.
// =====================================================================
__global__ __launch_bounds__(512, 1) void fused128d(
    const uint16_t* __restrict__ xbf,
    const uint16_t* __restrict__ W1t, const float* __restrict__ b1,
    const uint16_t* __restrict__ W2t, const float* __restrict__ b2,
    const uint16_t* __restrict__ W3t, const float* __restrict__ b3,
    float* __restrict__ out)
{
    extern __shared__ char smem[];
    char* h1buf = smem;             // 128KB: X [0:64K) + L1 W dbuf [64K:128K); h1 after
    char* wstg  = smem + 131072;    // 32KB:  L2 dbuf 2x16KB / h2q [128][256B]

    const int tid = threadIdx.x, wid = tid >> 6, lane = tid & 63;
    const int kg = lane >> 4, lr = lane & 15;
    const int e   = blockIdx.x;
    const int bm0 = blockIdx.y * 128;
    const int wm = wid >> 2, wn = wid & 3;        // L1/L2: 2m x 4n waves
    const int rlo = lane >> 3, pslot = lane & 7;
    const int lswz = (pslot ^ rlo) * 8;

    const uint16_t* Xb  = xbf + (size_t)bm0 * 256;
    const uint16_t* W1e = W1t + (size_t)e * 512 * 256;
    const uint16_t* W2e = W2t + (size_t)e * 512 * 512;
    const uint16_t* W3e = W3t + (size_t)e * 32 * 512;

    // L1 stage: W1 tile [256n][64k] (32KB) for n-half nh, k-tile kt -> slot s
    auto stageW1 = [&](int s, int nh, int kt) {
#pragma unroll
        for (int g = 0; g < 4; ++g) {
            const int rb = g * 64 + wid * 8;                 // +rlo: r&7==rlo
            gload16(W1e + (size_t)(nh * 256 + rb + rlo) * 256 + kt * 64 + lswz,
                    h1buf + 65536 + s * 32768 + rb * 128 + lane * 16);
        }
    };
    // L2 stage: W2 tile [128n][64k] (16KB) for n-quarter nq, k-tile kt
    auto stageW2 = [&](int cur, int nq, int kt) {
#pragma unroll
        for (int i = 0; i < 2; ++i) {
            const int rb = wid * 16 + i * 8;
            gload16(W2e + (size_t)(nq * 128 + rb + rlo) * 512 + kt * 64 + lswz,
                    wstg + cur * 16384 + rb * 128 + lane * 16);
        }
    };

    // ---- prologue: X [128][256] as 4 subtiles into h1buf[0:64K) ----
#pragma unroll
    for (int kt = 0; kt < 4; ++kt)
#pragma unroll
        for (int i = 0; i < 2; ++i) {
            const int rb = wid * 16 + i * 8;
            gload16(Xb + (size_t)(rb + rlo) * 256 + kt * 64 + lswz,
                    h1buf + kt * 16384 + rb * 128 + lane * 16);
        }
    stageW1(0, 0, 0);
    __syncthreads();

    // ======== LAYER 1 (K=256): 8 fat phases, acc in registers =========
    f32x4 a1[2][4][4];               // [nh][b][c] = 128 VGPR
#pragma unroll
    for (int q = 0; q < 2; ++q)
#pragma unroll
        for (int b = 0; b < 4; ++b)
#pragma unroll
            for (int c = 0; c < 4; ++c) a1[q][b][c] = f32x4{0.f, 0.f, 0.f, 0.f};

#pragma unroll
    for (int p = 0; p < 8; ++p) {    // p = nh*4 + kt
        const int nh = p >> 2, kt = p & 3, cur = p & 1;
        if (p + 1 < 8) stageW1(cur ^ 1, (p + 1) >> 2, (p + 1) & 3);
        asm volatile("" ::: "memory");
        const char* sW = h1buf + 65536 + cur * 32768;
        __builtin_amdgcn_s_setprio(1);
#pragma unroll
        for (int kh = 0; kh < 2; ++kh) {
            bf16x8 wf[4], af[4];
#pragma unroll
            for (int c = 0; c < 4; ++c) {
                const int row = wn * 64 + c * 16 + lr;
                wf[c] = *(const bf16x8*)(sW + row * 128 +
                                         (((kh * 4 + kg) ^ (row & 7)) << 4));
            }
#pragma unroll
            for (int b = 0; b < 4; ++b) {
                const int row = wm * 64 + b * 16 + lr;
                af[b] = *(const bf16x8*)(h1buf + kt * 16384 + row * 128 +
                                         (((kh * 4 + kg) ^ (row & 7)) << 4));
            }
#pragma unroll
            for (int b = 0; b < 4; ++b)
#pragma unroll
                for (int c = 0; c < 4; ++c)
                    a1[nh][b][c] = __builtin_amdgcn_mfma_f32_16x16x32_bf16(wf[c], af[b], a1[nh][b][c], 0, 0, 0);
        }
        __builtin_amdgcn_s_setprio(0);
        __syncthreads();
    }

    // ---- W2 prefetch (wstg idle all L1); epilogue sync drains it ----
    stageW2(0, 0, 0);

    // ---- L1 epilogue (X + W ring dead): bias+relu -> h1 swz32 ----
#pragma unroll
    for (int nh = 0; nh < 2; ++nh)
#pragma unroll
        for (int c = 0; c < 4; ++c) {
            const int col = nh * 256 + wn * 64 + c * 16 + kg * 4;
            const float4 bv = *(const float4*)(b1 + e * 512 + col);
#pragma unroll
            for (int b = 0; b < 4; ++b) {
                const float x0 = fmaxf(a1[nh][b][c][0] + bv.x, 0.f);
                const float x1 = fmaxf(a1[nh][b][c][1] + bv.y, 0.f);
                const float x2 = fmaxf(a1[nh][b][c][2] + bv.z, 0.f);
                const float x3 = fmaxf(a1[nh][b][c][3] + bv.w, 0.f);
                uint2 w;
                w.x = pk2bf(x0, x1);
                w.y = pk2bf(x2, x3);
                const int row = wm * 64 + b * 16 + lr;
                *(uint2*)(h1buf + row * 1024 + (((col << 1)) ^ ((row & 7) << 5))) = w;
            }
        }
    __syncthreads();                 // h1 visible + W2 tile0 drained

    // ========== LAYERS 2+3 per n-quarter (h2q -> wstg -> L3 partial) ====
    const int mf = wid >> 1, of = wid & 1;        // L3: 4m x 2o waves
    f32x4 o3[2];
    o3[0] = f32x4{0.f, 0.f, 0.f, 0.f};
    o3[1] = f32x4{0.f, 0.f, 0.f, 0.f};

#pragma unroll
    for (int nq = 0; nq < 4; ++nq) {
        if (nq > 0) {                // nq0's tile0 was prefetched pre-epilogue
            stageW2(0, nq, 0);
            __syncthreads();
        }

        f32x4 a2[4][2];
#pragma unroll
        for (int b = 0; b < 4; ++b)
#pragma unroll
            for (int c = 0; c < 2; ++c) a2[b][c] = f32x4{0.f, 0.f, 0.f, 0.f};

#pragma unroll
        for (int kt = 0; kt < 8; ++kt) {
            const int cur = kt & 1;
            if (kt + 1 < 8) stageW2(cur ^ 1, nq, kt + 1);
            asm volatile("" ::: "memory");
            __builtin_amdgcn_s_setprio(1);
#pragma unroll
            for (int kh = 0; kh < 2; ++kh) {
                bf16x8 wf[2], af[4];
#pragma unroll
                for (int c = 0; c < 2; ++c) {
                    const int row = wn * 32 + c * 16 + lr;
                    wf[c] = *(const bf16x8*)(wstg + cur * 16384 + row * 128 +
                                             (((kh * 4 + kg) ^ (row & 7)) << 4));
                }
                const int kbyte = kt * 128 + kh * 64 + kg * 16;
#pragma unroll
                for (int b = 0; b < 4; ++b) {
                    const int row = wm * 64 + b * 16 + lr;
                    af[b] = *(const bf16x8*)(h1buf + row * 1024 +
                                             (kbyte ^ ((row & 7) << 5)));
                }
#pragma unroll
                for (int b = 0; b < 4; ++b)
#pragma unroll
                    for (int c = 0; c < 2; ++c)
                        a2[b][c] = __builtin_amdgcn_mfma_f32_16x16x32_bf16(wf[c], af[b], a2[b][c], 0, 0, 0);
            }
            __builtin_amdgcn_s_setprio(0);
            __syncthreads();
        }

        // epilogue: bias+relu -> h2q in wstg [128][256B] swz32
#pragma unroll
        for (int c = 0; c < 2; ++c) {
            const int colh = wn * 32 + c * 16 + kg * 4;      // 0..127
            const float4 bv = *(const float4*)(b2 + e * 512 + nq * 128 + colh);
#pragma unroll
            for (int b = 0; b < 4; ++b) {
                const float x0 = fmaxf(a2[b][c][0] + bv.x, 0.f);
                const float x1 = fmaxf(a2[b][c][1] + bv.y, 0.f);
                const float x2 = fmaxf(a2[b][c][2] + bv.z, 0.f);
                const float x3 = fmaxf(a2[b][c][3] + bv.w, 0.f);
                uint2 w;
                w.x = pk2bf(x0, x1);
                w.y = pk2bf(x2, x3);
                const int row = wm * 64 + b * 16 + lr;
                *(uint2*)(wstg + row * 256 + (((colh << 1)) ^ ((row & 7) << 5))) = w;
            }
        }
        __syncthreads();

        // L3 partial: o3 += h2q @ W3[:, nq*128..+128)  (r10/r15/r16-verified)
#pragma unroll
        for (int kcq = 0; kcq < 4; ++kcq)
#pragma unroll
            for (int b2f = 0; b2f < 2; ++b2f) {
                const int row = mf * 32 + b2f * 16 + lr;
                const bf16x8 hb = *(const bf16x8*)(wstg + row * 256 +
                                                   ((kcq * 64 + kg * 16) ^ ((row & 7) << 5)));
                const bf16x8 w3 = *(const bf16x8*)(W3e + (size_t)(of * 16 + lr) * 512 +
                                                   nq * 128 + kcq * 32 + kg * 8);
                o3[b2f] = __builtin_amdgcn_mfma_f32_16x16x32_bf16(w3, hb, o3[b2f], 0, 0, 0);
            }
        __syncthreads();   // hb reads retired; wstg free for next nq
    }

    // ---- final store: bias3 + float4, row-contiguous ----
#pragma unroll
    for (int b2f = 0; b2f < 2; ++b2f) {
        const int col = e * 32 + of * 16 + kg * 4;
        const float4 bv = *(const float4*)(b3 + col);
        const int row = bm0 + mf * 32 + b2f * 16 + lr;
        float4 res;
        res.x = o3[b2f][0] + bv.x;
        res.y = o3[b2f][1] + bv.y;
        res.z = o3[b2f][2] + bv.z;
        res.w = o3[b2f][3] + bv.w;
        *(float4*)(out + (size_t)row * 256 + col) = res;
    }
}

// ---------------- host launch ----------------
extern "C" void kernel_launch(void* const* d_in, const int* in_sizes, int n_in,
                              void* d_out, int out_size, void* d_ws, size_t ws_size,
                              hipStream_t stream) {
    (void)in_sizes; (void)n_in; (void)out_size; (void)ws_size;
    const float* X  = (const float*)d_in[0];   // [16384,256]
    const float* W1 = (const float*)d_in[1];   // [8,256,512]
    const float* b1 = (const float*)d_in[2];   // [8,512]
    const float* W2 = (const float*)d_in[3];   // [8,512,512]
    const float* b2 = (const float*)d_in[4];   // [8,512]
    const float* W3 = (const float*)d_in[5];   // [8,512,32]
    const float* b3 = (const float*)d_in[6];   // [8,32]
    float* out = (float*)d_out;                // [16384,8,32]

    uint16_t* w1t = (uint16_t*)d_ws;           // [8][512][256] bf16  (2 MB)
    uint16_t* w2t = w1t + 8 * 256 * 512;       // [8][512][512] bf16  (4 MB)
    uint16_t* w3t = w2t + 8 * 512 * 512;       // [8][32][512]  bf16  (256 KB)
    uint16_t* xbf = w3t + 8 * 512 * 32;        // [16384][256]  bf16  (8 MB)

    prep<<<7296, 256, 0, stream>>>(X, W1, W2, W3, xbf, w1t, w2t, w3t);

    (void)hipFuncSetAttribute((const void*)fused128d,
                              hipFuncAttributeMaxDynamicSharedMemorySize, 163840);
    fused128d<<<dim3(8, 128), 512, 163840, stream>>>(xbf, w1t, b1, w2t, b2,
                                                     w3t, b3, out);
}

// Round 23
// 133.465 us; speedup vs baseline: 1.3329x; 1.0453x over previous
//
#include <hip/hip_runtime.h>
#include <stdint.h>

// ---------------- types ----------------
typedef short bf16x8 __attribute__((ext_vector_type(8)));
typedef float f32x4  __attribute__((ext_vector_type(4)));

__device__ __forceinline__ uint16_t f2bf(float f) {
    uint32_t u = __float_as_uint(f);
    u += 0x7FFF + ((u >> 16) & 1);   // round-to-nearest-even
    return (uint16_t)(u >> 16);
}
__device__ __forceinline__ uint32_t pk2bf(float a, float b) {
    return (uint32_t)f2bf(a) | ((uint32_t)f2bf(b) << 16);
}

typedef __attribute__((address_space(1))) const uint32_t gu32;
typedef __attribute__((address_space(3))) uint32_t lu32;
__device__ __forceinline__ void gload16(const void* g, void* l) {
    __builtin_amdgcn_global_load_lds((gu32*)g, (lu32*)l, 16, 0, 0);
}

// =====================================================================
// prep: all prologue work in one kernel (r13-16-verified).
// =====================================================================
__global__ __launch_bounds__(256) void prep(
    const float* __restrict__ X,  const float* __restrict__ W1,
    const float* __restrict__ W2, const float* __restrict__ W3,
    uint16_t* __restrict__ xbf, uint16_t* __restrict__ w1t,
    uint16_t* __restrict__ w2t, uint16_t* __restrict__ w3t)
{
    const int b = blockIdx.x, tid = threadIdx.x;
    if (b < 4096) {
        const int i = b * 256 + tid;
        const float4 v = ((const float4*)X)[i];
        ushort4 h;
        h.x = f2bf(v.x); h.y = f2bf(v.y); h.z = f2bf(v.z); h.w = f2bf(v.w);
        ((ushort4*)xbf)[i] = h;
        return;
    }
    __shared__ float t[32][33];
    const int tx = tid & 31, ty = tid >> 5;
    const float* in; uint16_t* out; int R, C, bx, by, e;
    if (b < 5120) {
        const int bb = b - 4096; e = bb >> 7; const int rem = bb & 127;
        bx = rem & 15; by = rem >> 4; R = 256; C = 512; in = W1; out = w1t;
    } else if (b < 7168) {
        const int bb = b - 5120; e = bb >> 8; const int rem = bb & 255;
        bx = rem & 15; by = rem >> 4; R = 512; C = 512; in = W2; out = w2t;
    } else {
        const int bb = b - 7168; e = bb >> 4; bx = 0; by = bb & 15;
        R = 512; C = 32; in = W3; out = w3t;
    }
    const int r0 = by * 32, c0 = bx * 32;
    const float* ine = in + (size_t)e * R * C;
    uint16_t* oute   = out + (size_t)e * R * C;
#pragma unroll
    for (int j = 0; j < 4; ++j)
        t[ty + 8 * j][tx] = ine[(size_t)(r0 + ty + 8 * j) * C + (c0 + tx)];
    __syncthreads();
#pragma unroll
    for (int j = 0; j < 4; ++j) {
        const int orow = c0 + ty + 8 * j;
        const int ocol = r0 + tx;
        oute[(size_t)orow * R + ocol] = f2bf(t[tx][ty + 8 * j]);
    }
}

// =====================================================================
// fused128e: r22 champion (139.5us) + two latency-hiding deltas:
//  1. BOTH wstg slots pre-staged during L1 (W2 kt0 AND kt1) -> L2-nq0
//     enters its K-loop with no entry stage+sync; kt-loop skips the
//     redundant nq0/kt0 stage. Slot audit: nq0-kt1 reads slot1
//     (pre-staged, drained by L1-epilogue sync); kt1 stages kt2->slot0
//     after kt0's sync retired tile0's readers. Engine invariants kept.
//  2. W3 fragment loads (b2f-invariant) hoisted to registers right
//     after each nq's K-loop -> their global latency hides under the
//     h2q epilogue + barrier instead of sitting on L3's critical path.
// Everything else r22-verbatim (fat L1 phases, swz32 h1/h2q, 16B-swz
// gload tiles, 2-phase engine, swapped-MFMA maps, epilogues, L3).
// =====================================================================
__global__ __launch_bounds__(512, 1) void fused128e(
    const uint16_t* __restrict__ xbf,
    const uint16_t* __restrict__ W1t, const float* __restrict__ b1,
    const uint16_t* __restrict__ W2t, const float* __restrict__ b2,
    const uint16_t* __restrict__ W3t, const float* __restrict__ b3,
    float* __restrict__ out)
{
    extern __shared__ char smem[];
    char* h1buf = smem;             // 128KB: X [0:64K) + L1 W dbuf [64K:128K); h1 after
    char* wstg  = smem + 131072;    // 32KB:  L2 dbuf 2x16KB / h2q [128][256B]

    const int tid = threadIdx.x, wid = tid >> 6, lane = tid & 63;
    const int kg = lane >> 4, lr = lane & 15;
    const int e   = blockIdx.x;
    const int bm0 = blockIdx.y * 128;
    const int wm = wid >> 2, wn = wid & 3;        // L1/L2: 2m x 4n waves
    const int rlo = lane >> 3, pslot = lane & 7;
    const int lswz = (pslot ^ rlo) * 8;

    const uint16_t* Xb  = xbf + (size_t)bm0 * 256;
    const uint16_t* W1e = W1t + (size_t)e * 512 * 256;
    const uint16_t* W2e = W2t + (size_t)e * 512 * 512;
    const uint16_t* W3e = W3t + (size_t)e * 32 * 512;

    // L1 stage: W1 tile [256n][64k] (32KB) for n-half nh, k-tile kt -> slot s
    auto stageW1 = [&](int s, int nh, int kt) {
#pragma unroll
        for (int g = 0; g < 4; ++g) {
            const int rb = g * 64 + wid * 8;                 // +rlo: r&7==rlo
            gload16(W1e + (size_t)(nh * 256 + rb + rlo) * 256 + kt * 64 + lswz,
                    h1buf + 65536 + s * 32768 + rb * 128 + lane * 16);
        }
    };
    // L2 stage: W2 tile [128n][64k] (16KB) for n-quarter nq, k-tile kt
    auto stageW2 = [&](int cur, int nq, int kt) {
#pragma unroll
        for (int i = 0; i < 2; ++i) {
            const int rb = wid * 16 + i * 8;
            gload16(W2e + (size_t)(nq * 128 + rb + rlo) * 512 + kt * 64 + lswz,
                    wstg + cur * 16384 + rb * 128 + lane * 16);
        }
    };

    // ---- prologue: X [128][256] as 4 subtiles into h1buf[0:64K) ----
#pragma unroll
    for (int kt = 0; kt < 4; ++kt)
#pragma unroll
        for (int i = 0; i < 2; ++i) {
            const int rb = wid * 16 + i * 8;
            gload16(Xb + (size_t)(rb + rlo) * 256 + kt * 64 + lswz,
                    h1buf + kt * 16384 + rb * 128 + lane * 16);
        }
    stageW1(0, 0, 0);
    __syncthreads();

    // ======== LAYER 1 (K=256): 8 fat phases, acc in registers =========
    f32x4 a1[2][4][4];               // [nh][b][c] = 128 VGPR
#pragma unroll
    for (int q = 0; q < 2; ++q)
#pragma unroll
        for (int b = 0; b < 4; ++b)
#pragma unroll
            for (int c = 0; c < 4; ++c) a1[q][b][c] = f32x4{0.f, 0.f, 0.f, 0.f};

#pragma unroll
    for (int p = 0; p < 8; ++p) {    // p = nh*4 + kt
        const int nh = p >> 2, kt = p & 3, cur = p & 1;
        if (p + 1 < 8) stageW1(cur ^ 1, (p + 1) >> 2, (p + 1) & 3);
        asm volatile("" ::: "memory");
        const char* sW = h1buf + 65536 + cur * 32768;
        __builtin_amdgcn_s_setprio(1);
#pragma unroll
        for (int kh = 0; kh < 2; ++kh) {
            bf16x8 wf[4], af[4];
#pragma unroll
            for (int c = 0; c < 4; ++c) {
                const int row = wn * 64 + c * 16 + lr;
                wf[c] = *(const bf16x8*)(sW + row * 128 +
                                         (((kh * 4 + kg) ^ (row & 7)) << 4));
            }
#pragma unroll
            for (int b = 0; b < 4; ++b) {
                const int row = wm * 64 + b * 16 + lr;
                af[b] = *(const bf16x8*)(h1buf + kt * 16384 + row * 128 +
                                         (((kh * 4 + kg) ^ (row & 7)) << 4));
            }
#pragma unroll
            for (int b = 0; b < 4; ++b)
#pragma unroll
                for (int c = 0; c < 4; ++c)
                    a1[nh][b][c] = __builtin_amdgcn_mfma_f32_16x16x32_bf16(wf[c], af[b], a1[nh][b][c], 0, 0, 0);
        }
        __builtin_amdgcn_s_setprio(0);
        __syncthreads();
    }

    // ---- W2 prefetch: BOTH slots (kt0 + kt1); epilogue sync drains ----
    stageW2(0, 0, 0);
    stageW2(1, 0, 1);

    // ---- L1 epilogue (X + W ring dead): bias+relu -> h1 swz32 ----
#pragma unroll
    for (int nh = 0; nh < 2; ++nh)
#pragma unroll
        for (int c = 0; c < 4; ++c) {
            const int col = nh * 256 + wn * 64 + c * 16 + kg * 4;
            const float4 bv = *(const float4*)(b1 + e * 512 + col);
#pragma unroll
            for (int b = 0; b < 4; ++b) {
                const float x0 = fmaxf(a1[nh][b][c][0] + bv.x, 0.f);
                const float x1 = fmaxf(a1[nh][b][c][1] + bv.y, 0.f);
                const float x2 = fmaxf(a1[nh][b][c][2] + bv.z, 0.f);
                const float x3 = fmaxf(a1[nh][b][c][3] + bv.w, 0.f);
                uint2 w;
                w.x = pk2bf(x0, x1);
                w.y = pk2bf(x2, x3);
                const int row = wm * 64 + b * 16 + lr;
                *(uint2*)(h1buf + row * 1024 + (((col << 1)) ^ ((row & 7) << 5))) = w;
            }
        }
    __syncthreads();                 // h1 visible + W2 kt0,kt1 drained

    // ========== LAYERS 2+3 per n-quarter (h2q -> wstg -> L3 partial) ====
    const int mf = wid >> 1, of = wid & 1;        // L3: 4m x 2o waves
    f32x4 o3[2];
    o3[0] = f32x4{0.f, 0.f, 0.f, 0.f};
    o3[1] = f32x4{0.f, 0.f, 0.f, 0.f};

#pragma unroll
    for (int nq = 0; nq < 4; ++nq) {
        if (nq > 0) {                // nq0: both tiles pre-staged during L1
            stageW2(0, nq, 0);
            __syncthreads();
        }

        f32x4 a2[4][2];
#pragma unroll
        for (int b = 0; b < 4; ++b)
#pragma unroll
            for (int c = 0; c < 2; ++c) a2[b][c] = f32x4{0.f, 0.f, 0.f, 0.f};

#pragma unroll
        for (int kt = 0; kt < 8; ++kt) {
            const int cur = kt & 1;
            if (kt + 1 < 8 && !(nq == 0 && kt == 0))
                stageW2(cur ^ 1, nq, kt + 1);
            asm volatile("" ::: "memory");
            __builtin_amdgcn_s_setprio(1);
#pragma unroll
            for (int kh = 0; kh < 2; ++kh) {
                bf16x8 wf[2], af[4];
#pragma unroll
                for (int c = 0; c < 2; ++c) {
                    const int row = wn * 32 + c * 16 + lr;
                    wf[c] = *(const bf16x8*)(wstg + cur * 16384 + row * 128 +
                                             (((kh * 4 + kg) ^ (row & 7)) << 4));
                }
                const int kbyte = kt * 128 + kh * 64 + kg * 16;
#pragma unroll
                for (int b = 0; b < 4; ++b) {
                    const int row = wm * 64 + b * 16 + lr;
                    af[b] = *(const bf16x8*)(h1buf + row * 1024 +
                                             (kbyte ^ ((row & 7) << 5)));
                }
#pragma unroll
                for (int b = 0; b < 4; ++b)
#pragma unroll
                    for (int c = 0; c < 2; ++c)
                        a2[b][c] = __builtin_amdgcn_mfma_f32_16x16x32_bf16(wf[c], af[b], a2[b][c], 0, 0, 0);
            }
            __builtin_amdgcn_s_setprio(0);
            __syncthreads();
        }

        // ---- W3 hoist: 4 b128 loads issue now; latency hides under
        //      the h2q epilogue + barrier (b2f-invariant values) ----
        bf16x8 w3r[4];
#pragma unroll
        for (int kcq = 0; kcq < 4; ++kcq)
            w3r[kcq] = *(const bf16x8*)(W3e + (size_t)(of * 16 + lr) * 512 +
                                        nq * 128 + kcq * 32 + kg * 8);

        // epilogue: bias+relu -> h2q in wstg [128][256B] swz32
#pragma unroll
        for (int c = 0; c < 2; ++c) {
            const int colh = wn * 32 + c * 16 + kg * 4;      // 0..127
            const float4 bv = *(const float4*)(b2 + e * 512 + nq * 128 + colh);
#pragma unroll
            for (int b = 0; b < 4; ++b) {
                const float x0 = fmaxf(a2[b][c][0] + bv.x, 0.f);
                const float x1 = fmaxf(a2[b][c][1] + bv.y, 0.f);
                const float x2 = fmaxf(a2[b][c][2] + bv.z, 0.f);
                const float x3 = fmaxf(a2[b][c][3] + bv.w, 0.f);
                uint2 w;
                w.x = pk2bf(x0, x1);
                w.y = pk2bf(x2, x3);
                const int row = wm * 64 + b * 16 + lr;
                *(uint2*)(wstg + row * 256 + (((colh << 1)) ^ ((row & 7) << 5))) = w;
            }
        }
        __syncthreads();

        // L3 partial: o3 += h2q @ W3[:, nq*128..+128)  (r10/r15/r16-verified)
#pragma unroll
        for (int kcq = 0; kcq < 4; ++kcq)
#pragma unroll
            for (int b2f = 0; b2f < 2; ++b2f) {
                const int row = mf * 32 + b2f * 16 + lr;
                const bf16x8 hb = *(const bf16x8*)(wstg + row * 256 +
                                                   ((kcq * 64 + kg * 16) ^ ((row & 7) << 5)));
                o3[b2f] = __builtin_amdgcn_mfma_f32_16x16x32_bf16(w3r[kcq], hb, o3[b2f], 0, 0, 0);
            }
        __syncthreads();   // hb reads retired; wstg free for next nq
    }

    // ---- final store: bias3 + float4, row-contiguous ----
#pragma unroll
    for (int b2f = 0; b2f < 2; ++b2f) {
        const int col = e * 32 + of * 16 + kg * 4;
        const float4 bv = *(const float4*)(b3 + col);
        const int row = bm0 + mf * 32 + b2f * 16 + lr;
        float4 res;
        res.x = o3[b2f][0] + bv.x;
        res.y = o3[b2f][1] + bv.y;
        res.z = o3[b2f][2] + bv.z;
        res.w = o3[b2f][3] + bv.w;
        *(float4*)(out + (size_t)row * 256 + col) = res;
    }
}

// ---------------- host launch ----------------
extern "C" void kernel_launch(void* const* d_in, const int* in_sizes, int n_in,
                              void* d_out, int out_size, void* d_ws, size_t ws_size,
                              hipStream_t stream) {
    (void)in_sizes; (void)n_in; (void)out_size; (void)ws_size;
    const float* X  = (const float*)d_in[0];   // [16384,256]
    const float* W1 = (const float*)d_in[1];   // [8,256,512]
    const float* b1 = (const float*)d_in[2];   // [8,512]
    const float* W2 = (const float*)d_in[3];   // [8,512,512]
    const float* b2 = (const float*)d_in[4];   // [8,512]
    const float* W3 = (const float*)d_in[5];   // [8,512,32]
    const float* b3 = (const float*)d_in[6];   // [8,32]
    float* out = (float*)d_out;                // [16384,8,32]

    uint16_t* w1t = (uint16_t*)d_ws;           // [8][512][256] bf16  (2 MB)
    uint16_t* w2t = w1t + 8 * 256 * 512;       // [8][512][512] bf16  (4 MB)
    uint16_t* w3t = w2t + 8 * 512 * 512;       // [8][32][512]  bf16  (256 KB)
    uint16_t* xbf = w3t + 8 * 512 * 32;        // [16384][256]  bf16  (8 MB)

    prep<<<7296, 256, 0, stream>>>(X, W1, W2, W3, xbf, w1t, w2t, w3t);

    (void)hipFuncSetAttribute((const void*)fused128e,
                              hipFuncAttributeMaxDynamicSharedMemorySize, 163840);
    fused128e<<<dim3(8, 128), 512, 163840, stream>>>(xbf, w1t, b1, w2t, b2,
                                                     w3t, b3, out);
}